// Round 1
// baseline (1464.067 us; speedup 1.0000x reference)
//
#include <hip/hip_runtime.h>
#include <math.h>

#define B_DIM 2
#define S_DIM 2048
#define D_DIM 1024
#define H_NUM 16
#define DH    64
#define M_DIM (B_DIM * S_DIM) /* 4096 */

// ---------------------------------------------------------------------------
// GEMM: C = A @ W^T (+ bias). A:[M,K] row-major, W:[N,K] row-major.
// mode 0: C[m*N+n]                     (Q, V projections)
// mode 1: K-transpose epilogue -> Kt[((b*H+h)*DH+d)*S + s]   (K projection)
// mode 2: C[m*N+n] = acc + bias[n]     (output projection)
// ---------------------------------------------------------------------------
#define TILE 64
#define BKK  16

__global__ __launch_bounds__(256)
void gemm_xwT(const float* __restrict__ A, const float* __restrict__ W,
              float* __restrict__ C, const float* __restrict__ bias, int mode)
{
    __shared__ float As[BKK][TILE + 4];
    __shared__ float Bs[BKK][TILE + 4];
    const int K = D_DIM, N = D_DIM;
    const int n0 = blockIdx.x * TILE;
    const int m0 = blockIdx.y * TILE;
    const int t  = threadIdx.x;
    const int kq  = t & 3;   // which float4 along k
    const int row = t >> 2;  // 0..63
    const int tx = t & 15, ty = t >> 4;

    float acc[4][4];
#pragma unroll
    for (int i = 0; i < 4; ++i)
#pragma unroll
        for (int j = 0; j < 4; ++j) acc[i][j] = 0.f;

    for (int kt = 0; kt < K; kt += BKK) {
        const float4 a4 = *(const float4*)&A[(size_t)(m0 + row) * K + kt + kq * 4];
        const float4 b4 = *(const float4*)&W[(size_t)(n0 + row) * K + kt + kq * 4];
        As[kq * 4 + 0][row] = a4.x; As[kq * 4 + 1][row] = a4.y;
        As[kq * 4 + 2][row] = a4.z; As[kq * 4 + 3][row] = a4.w;
        Bs[kq * 4 + 0][row] = b4.x; Bs[kq * 4 + 1][row] = b4.y;
        Bs[kq * 4 + 2][row] = b4.z; Bs[kq * 4 + 3][row] = b4.w;
        __syncthreads();
#pragma unroll
        for (int kk = 0; kk < BKK; ++kk) {
            const float4 av4 = *(const float4*)&As[kk][ty * 4];
            const float4 bv4 = *(const float4*)&Bs[kk][tx * 4];
            const float av[4] = {av4.x, av4.y, av4.z, av4.w};
            const float bv[4] = {bv4.x, bv4.y, bv4.z, bv4.w};
#pragma unroll
            for (int i = 0; i < 4; ++i)
#pragma unroll
                for (int j = 0; j < 4; ++j)
                    acc[i][j] = fmaf(av[i], bv[j], acc[i][j]);
        }
        __syncthreads();
    }

#pragma unroll
    for (int i = 0; i < 4; ++i) {
        const int m = m0 + ty * 4 + i;
#pragma unroll
        for (int j = 0; j < 4; ++j) {
            const int n = n0 + tx * 4 + j;
            const float v = acc[i][j];
            if (mode == 0) {
                C[(size_t)m * N + n] = v;
            } else if (mode == 1) {
                const int h = n >> 6, d = n & 63;
                const int b = m >> 11, s = m & (S_DIM - 1);
                C[(((size_t)((b * H_NUM + h) * DH + d)) << 11) + s] = v;
            } else {
                C[(size_t)m * N + n] = v + bias[n];
            }
        }
    }
}

// ---------------------------------------------------------------------------
// Flash-style attention. One wave handles QT=8 query rows of one (b,h).
// Keys processed in chunks of KC=64 (one key per lane) with online softmax.
// PV pass: lane owns output dim d=lane; weights exchanged via small LDS buf.
// Q:[B*S, D] (=[b,s,h,dh]) ; Kt:[B,H,DH,S] ; V:[B*S, D] ; Y:[B*S, D]
// ---------------------------------------------------------------------------
#define QT 8
#define KC 64

__global__ __launch_bounds__(256)
void attn_fwd(const float* __restrict__ Q, const float* __restrict__ Kt,
              const float* __restrict__ V, float* __restrict__ Y)
{
    __shared__ float qs[4][DH][QT];   // [wave][d][qi], broadcast reads
    __shared__ float wsh[4][KC][QT];  // [wave][key-in-chunk][qi]

    const int w    = threadIdx.x >> 6;
    const int lane = threadIdx.x & 63;
    const int task = blockIdx.x * 4 + w;       // 0..8191
    const int NQT  = S_DIM / QT;               // 256 q-tiles per (b,h)
    const int qt   = task & (NQT - 1);
    const int bh   = task >> 8;                // consecutive blocks share bh -> L2 reuse
    const int b    = bh >> 4;
    const int h    = bh & (H_NUM - 1);
    const int q0   = qt * QT;
    const float scale = 0.125f;                // 1/sqrt(64)

#pragma unroll
    for (int qi = 0; qi < QT; ++qi)
        qs[w][lane][qi] =
            Q[((size_t)(b * S_DIM + q0 + qi)) * D_DIM + h * DH + lane] * scale;

    float mx[QT], ls[QT], y[QT];
#pragma unroll
    for (int qi = 0; qi < QT; ++qi) { mx[qi] = -1e30f; ls[qi] = 0.f; y[qi] = 0.f; }

    const float* kbase = Kt + ((size_t)bh * DH) * S_DIM;
    const float* vbase = V + ((size_t)b * S_DIM) * D_DIM + h * DH + lane;
    __syncthreads();

    for (int kb = 0; kb < S_DIM / KC; ++kb) {
        // ---- scores for this chunk: lane owns key = kb*KC + lane ----
        const float* kp = kbase + kb * KC + lane;
        float s[QT];
#pragma unroll
        for (int qi = 0; qi < QT; ++qi) s[qi] = 0.f;
#pragma unroll 4
        for (int d = 0; d < DH; ++d) {
            const float kv = kp[(size_t)d * S_DIM];   // coalesced across lanes
#pragma unroll
            for (int qi = 0; qi < QT; ++qi)
                s[qi] = fmaf(qs[w][d][qi], kv, s[qi]);
        }
        // ---- online softmax update ----
#pragma unroll
        for (int qi = 0; qi < QT; ++qi) {
            float r = s[qi];
#pragma unroll
            for (int off = 32; off > 0; off >>= 1)
                r = fmaxf(r, __shfl_xor(r, off, 64));
            const float nm = fmaxf(mx[qi], r);
            const float al = __expf(mx[qi] - nm);
            const float wv = __expf(s[qi] - nm);
            mx[qi] = nm;
            ls[qi] = ls[qi] * al + wv;   // per-lane partial of l
            y[qi] *= al;
            wsh[w][lane][qi] = wv;
        }
        __syncthreads();
        // ---- PV: lane owns dim d = lane ----
        const float* vp = vbase + (size_t)kb * KC * D_DIM;
#pragma unroll 4
        for (int k2 = 0; k2 < KC; ++k2) {
            const float vv = vp[(size_t)k2 * D_DIM];  // coalesced across lanes
#pragma unroll
            for (int qi = 0; qi < QT; ++qi)
                y[qi] = fmaf(wsh[w][k2][qi], vv, y[qi]);
        }
        __syncthreads();
    }

#pragma unroll
    for (int qi = 0; qi < QT; ++qi) {
        float r = ls[qi];
#pragma unroll
        for (int off = 32; off > 0; off >>= 1)
            r += __shfl_xor(r, off, 64);
        Y[((size_t)(b * S_DIM + q0 + qi)) * D_DIM + h * DH + lane] = y[qi] / r;
    }
}

// ---------------------------------------------------------------------------
extern "C" void kernel_launch(void* const* d_in, const int* in_sizes, int n_in,
                              void* d_out, int out_size, void* d_ws, size_t ws_size,
                              hipStream_t stream)
{
    const float* x  = (const float*)d_in[0];
    const float* wq = (const float*)d_in[1];
    const float* wk = (const float*)d_in[2];
    const float* wv = (const float*)d_in[3];
    const float* wo = (const float*)d_in[4];
    const float* bo = (const float*)d_in[5];
    float* out = (float*)d_out;
    float* ws  = (float*)d_ws;

    const size_t MD = (size_t)M_DIM * D_DIM;  // 4M floats
    if (ws_size < 4 * MD * sizeof(float)) return;  // need 64 MB scratch
    float* Qb  = ws;
    float* Ktb = ws + MD;
    float* Vb  = ws + 2 * MD;
    float* Yb  = ws + 3 * MD;

    dim3 g(D_DIM / TILE, M_DIM / TILE);
    dim3 blk(256);
    gemm_xwT<<<g, blk, 0, stream>>>(x, wq, Qb,  nullptr, 0);
    gemm_xwT<<<g, blk, 0, stream>>>(x, wk, Ktb, nullptr, 1);
    gemm_xwT<<<g, blk, 0, stream>>>(x, wv, Vb,  nullptr, 0);
    attn_fwd<<<dim3(B_DIM * H_NUM * (S_DIM / QT) / 4), blk, 0, stream>>>(Qb, Ktb, Vb, Yb);
    gemm_xwT<<<g, blk, 0, stream>>>(Yb, wo, out, bo, 2);
}

// Round 2
// 694.086 us; speedup vs baseline: 2.1093x; 2.1093x over previous
//
#include <hip/hip_runtime.h>
#include <math.h>

#define B_DIM 2
#define S_DIM 2048
#define D_DIM 1024
#define H_NUM 16
#define DH    64
#define M_DIM (B_DIM * S_DIM) /* 4096 */

typedef __attribute__((ext_vector_type(8))) short short8;
typedef __attribute__((ext_vector_type(4))) float float4v;
typedef __attribute__((ext_vector_type(4))) unsigned short ushort4v;

static __device__ __forceinline__ unsigned short f2bf(float f) {
    unsigned u = __float_as_uint(f);
    u += 0x7fffu + ((u >> 16) & 1u);
    return (unsigned short)(u >> 16);
}

// ---------------------------------------------------------------------------
// GEMM: C = A @ W^T (+ bias). A:[M,K] row-major, W:[N,K] row-major. fp32 math.
// mode 0: bf16 out, [B,H,S,Dh] layout      (Q and K)
// mode 1: bf16 out, [B,H,Dh,S] layout      (V transposed)
// mode 2: fp32 out, C[m*N+n] = acc+bias[n] (output projection)
// ---------------------------------------------------------------------------
#define TILE 64
#define BKK  16

__global__ __launch_bounds__(256)
void gemm_xwT(const float* __restrict__ A, const float* __restrict__ W,
              void* __restrict__ Cv, const float* __restrict__ bias, int mode)
{
    __shared__ float As[BKK][TILE + 4];
    __shared__ float Bs[BKK][TILE + 4];
    const int K = D_DIM, N = D_DIM;
    const int n0 = blockIdx.x * TILE;
    const int m0 = blockIdx.y * TILE;
    const int t  = threadIdx.x;
    const int kq  = t & 3;
    const int row = t >> 2;
    const int tx = t & 15, ty = t >> 4;

    float acc[4][4];
#pragma unroll
    for (int i = 0; i < 4; ++i)
#pragma unroll
        for (int j = 0; j < 4; ++j) acc[i][j] = 0.f;

    for (int kt = 0; kt < K; kt += BKK) {
        const float4 a4 = *(const float4*)&A[(size_t)(m0 + row) * K + kt + kq * 4];
        const float4 b4 = *(const float4*)&W[(size_t)(n0 + row) * K + kt + kq * 4];
        As[kq * 4 + 0][row] = a4.x; As[kq * 4 + 1][row] = a4.y;
        As[kq * 4 + 2][row] = a4.z; As[kq * 4 + 3][row] = a4.w;
        Bs[kq * 4 + 0][row] = b4.x; Bs[kq * 4 + 1][row] = b4.y;
        Bs[kq * 4 + 2][row] = b4.z; Bs[kq * 4 + 3][row] = b4.w;
        __syncthreads();
#pragma unroll
        for (int kk = 0; kk < BKK; ++kk) {
            const float4 av4 = *(const float4*)&As[kk][ty * 4];
            const float4 bv4 = *(const float4*)&Bs[kk][tx * 4];
            const float av[4] = {av4.x, av4.y, av4.z, av4.w};
            const float bv[4] = {bv4.x, bv4.y, bv4.z, bv4.w};
#pragma unroll
            for (int i = 0; i < 4; ++i)
#pragma unroll
                for (int j = 0; j < 4; ++j)
                    acc[i][j] = fmaf(av[i], bv[j], acc[i][j]);
        }
        __syncthreads();
    }

    const int h  = n0 >> 6;           // tx*4+j < 64, n0 is a multiple of 64
    const int d0 = tx * 4;
    if (mode == 0) {
        unsigned short* C = (unsigned short*)Cv;
#pragma unroll
        for (int i = 0; i < 4; ++i) {
            const int m = m0 + ty * 4 + i;
            const int b = m >> 11, s = m & (S_DIM - 1);
            ushort4v p;
#pragma unroll
            for (int j = 0; j < 4; ++j) p[j] = f2bf(acc[i][j]);
            *(ushort4v*)&C[(((size_t)(b * H_NUM + h) * S_DIM + s) << 6) + d0] = p;
        }
    } else if (mode == 1) {
        unsigned short* C = (unsigned short*)Cv;
        const int s0 = m0 + ty * 4;
        const int b = s0 >> 11, s = s0 & (S_DIM - 1);
#pragma unroll
        for (int j = 0; j < 4; ++j) {
            ushort4v p;
#pragma unroll
            for (int i = 0; i < 4; ++i) p[i] = f2bf(acc[i][j]);
            *(ushort4v*)&C[(((size_t)(b * H_NUM + h) * DH + d0 + j) << 11) + s] = p;
        }
    } else {
        float* C = (float*)Cv;
#pragma unroll
        for (int i = 0; i < 4; ++i) {
            const int m = m0 + ty * 4 + i;
#pragma unroll
            for (int j = 0; j < 4; ++j) {
                const int n = n0 + tx * 4 + j;
                C[(size_t)m * N + n] = acc[i][j] + bias[n];
            }
        }
    }
}

// ---------------------------------------------------------------------------
// MFMA flash attention. Wave = 32 queries (2 row-tiles of 16) of one (b,h).
// Keys in chunks of 64, online softmax. All MFMA operands are 16B global
// loads (Qh,Kh:[B,H,S,Dh] bf16; Vt:[B,H,Dh,S] bf16). LDS only for the
// per-wave P C-layout -> A-layout round-trip (no barriers in the loop).
// ---------------------------------------------------------------------------
#define P_LD 72   /* 16-row leading dim, 144B: 16B-aligned, bank-skewed */

__global__ __launch_bounds__(256)
void attn_mfma(const unsigned short* __restrict__ Qh,
               const unsigned short* __restrict__ Kh,
               const unsigned short* __restrict__ Vt,
               float* __restrict__ Y)
{
    __shared__ short Pb[4][2][16][P_LD];

    const int w    = threadIdx.x >> 6;
    const int lane = threadIdx.x & 63;
    const int n    = lane & 15;       // MFMA col / A-row index
    const int quad = lane >> 4;       // 0..3

    const int wave_id = blockIdx.x * 4 + w;     // 0..2047
    const int bh    = wave_id >> 6;             // 64 waves per (b,h)
    const int qbase = (wave_id & 63) * 32;
    const int b     = bh >> 4;
    const int h     = bh & (H_NUM - 1);

    const unsigned short* Qb = Qh + (((size_t)bh * S_DIM) << 6);
    const unsigned short* Kb = Kh + (((size_t)bh * S_DIM) << 6);
    const unsigned short* Vb = Vt + (((size_t)bh * DH) << 11);

    // Q fragments: qa[mt][kc] covers rows qbase+mt*16+(lane&15), k = kc*32+quad*8+j
    short8 qa[2][2];
#pragma unroll
    for (int mt = 0; mt < 2; ++mt)
#pragma unroll
        for (int kc = 0; kc < 2; ++kc)
            qa[mt][kc] = *(const short8*)&Qb[((size_t)(qbase + mt * 16 + n) << 6) + kc * 32 + quad * 8];

    float4v O[2][4];
    float   mrow[2][4], lrow[2][4];
#pragma unroll
    for (int mt = 0; mt < 2; ++mt) {
#pragma unroll
        for (int nt = 0; nt < 4; ++nt) O[mt][nt] = (float4v){0.f, 0.f, 0.f, 0.f};
#pragma unroll
        for (int r = 0; r < 4; ++r) { mrow[mt][r] = -1e30f; lrow[mt][r] = 0.f; }
    }

    const float SCALE = 0.125f;  // 1/sqrt(64), exact in fp32

    for (int kb = 0; kb < S_DIM / 64; ++kb) {
        const int key0 = kb * 64;
        // ---- K fragments for this 64-key chunk (shared by both m-tiles) ----
        short8 kf[4][2];
#pragma unroll
        for (int ct = 0; ct < 4; ++ct)
#pragma unroll
            for (int kc = 0; kc < 2; ++kc)
                kf[ct][kc] = *(const short8*)&Kb[((size_t)(key0 + ct * 16 + n) << 6) + kc * 32 + quad * 8];

        // ---- scores ----
        float4v s[2][4];
#pragma unroll
        for (int mt = 0; mt < 2; ++mt)
#pragma unroll
            for (int ct = 0; ct < 4; ++ct) {
                float4v acc = (float4v){0.f, 0.f, 0.f, 0.f};
                acc = __builtin_amdgcn_mfma_f32_16x16x32_bf16(qa[mt][0], kf[ct][0], acc, 0, 0, 0);
                acc = __builtin_amdgcn_mfma_f32_16x16x32_bf16(qa[mt][1], kf[ct][1], acc, 0, 0, 0);
                s[mt][ct] = acc;
            }

        // ---- V fragments (shared by both m-tiles) ----
        short8 vf[4][2];
#pragma unroll
        for (int nt = 0; nt < 4; ++nt)
#pragma unroll
            for (int kc = 0; kc < 2; ++kc)
                vf[nt][kc] = *(const short8*)&Vb[((size_t)(nt * 16 + n) << 11) + key0 + kc * 32 + quad * 8];

        // ---- online softmax + P round-trip + PV, per m-tile ----
#pragma unroll
        for (int mt = 0; mt < 2; ++mt) {
#pragma unroll
            for (int r = 0; r < 4; ++r) {
                const float a0 = s[mt][0][r] * SCALE;
                const float a1 = s[mt][1][r] * SCALE;
                const float a2 = s[mt][2][r] * SCALE;
                const float a3 = s[mt][3][r] * SCALE;
                float cm = fmaxf(fmaxf(a0, a1), fmaxf(a2, a3));
                cm = fmaxf(cm, __shfl_xor(cm, 1, 64));
                cm = fmaxf(cm, __shfl_xor(cm, 2, 64));
                cm = fmaxf(cm, __shfl_xor(cm, 4, 64));
                cm = fmaxf(cm, __shfl_xor(cm, 8, 64));
                const float mnew  = fmaxf(mrow[mt][r], cm);
                const float alpha = __expf(mrow[mt][r] - mnew);
                mrow[mt][r] = mnew;
                const float p0 = __expf(a0 - mnew);
                const float p1 = __expf(a1 - mnew);
                const float p2 = __expf(a2 - mnew);
                const float p3 = __expf(a3 - mnew);
                lrow[mt][r] = lrow[mt][r] * alpha + (p0 + p1 + p2 + p3);
#pragma unroll
                for (int nt = 0; nt < 4; ++nt) {
                    O[mt][nt][r] *= alpha;
                }
                const int prow = quad * 4 + r;
                Pb[w][mt][prow][0 * 16 + n] = (short)f2bf(p0);
                Pb[w][mt][prow][1 * 16 + n] = (short)f2bf(p1);
                Pb[w][mt][prow][2 * 16 + n] = (short)f2bf(p2);
                Pb[w][mt][prow][3 * 16 + n] = (short)f2bf(p3);
            }
            // P: C-layout in LDS -> A-operand fragments (same wave; no barrier)
            const short8 pa0 = *(const short8*)&Pb[w][mt][n][quad * 8];
            const short8 pa1 = *(const short8*)&Pb[w][mt][n][32 + quad * 8];
#pragma unroll
            for (int nt = 0; nt < 4; ++nt) {
                O[mt][nt] = __builtin_amdgcn_mfma_f32_16x16x32_bf16(pa0, vf[nt][0], O[mt][nt], 0, 0, 0);
                O[mt][nt] = __builtin_amdgcn_mfma_f32_16x16x32_bf16(pa1, vf[nt][1], O[mt][nt], 0, 0, 0);
            }
        }
    }

    // ---- epilogue: normalize and store fp32 ----
#pragma unroll
    for (int mt = 0; mt < 2; ++mt) {
        float linv[4];
#pragma unroll
        for (int r = 0; r < 4; ++r) {
            float ls = lrow[mt][r];
            ls += __shfl_xor(ls, 1, 64);
            ls += __shfl_xor(ls, 2, 64);
            ls += __shfl_xor(ls, 4, 64);
            ls += __shfl_xor(ls, 8, 64);
            linv[r] = 1.f / ls;
        }
#pragma unroll
        for (int nt = 0; nt < 4; ++nt)
#pragma unroll
            for (int r = 0; r < 4; ++r) {
                const int q = qbase + mt * 16 + quad * 4 + r;
                Y[((size_t)(b * S_DIM + q) << 10) + h * DH + nt * 16 + n] =
                    O[mt][nt][r] * linv[r];
            }
    }
}

// ---------------------------------------------------------------------------
extern "C" void kernel_launch(void* const* d_in, const int* in_sizes, int n_in,
                              void* d_out, int out_size, void* d_ws, size_t ws_size,
                              hipStream_t stream)
{
    const float* x  = (const float*)d_in[0];
    const float* wq = (const float*)d_in[1];
    const float* wk = (const float*)d_in[2];
    const float* wv = (const float*)d_in[3];
    const float* wo = (const float*)d_in[4];
    const float* bo = (const float*)d_in[5];
    float* out = (float*)d_out;

    const size_t MD = (size_t)M_DIM * D_DIM;  // 4M elements
    unsigned short* Qh = (unsigned short*)d_ws;          //  8 MB bf16 [B,H,S,Dh]
    unsigned short* Kh = Qh + MD;                        //  8 MB bf16 [B,H,S,Dh]
    unsigned short* Vt = Kh + MD;                        //  8 MB bf16 [B,H,Dh,S]
    float*          Yb = (float*)(Vt + MD);              // 16 MB fp32 [M,D]
    if (ws_size < 40u * 1024u * 1024u) return;

    dim3 g(D_DIM / TILE, M_DIM / TILE);
    dim3 blk(256);
    gemm_xwT<<<g, blk, 0, stream>>>(x, wq, Qh, nullptr, 0);
    gemm_xwT<<<g, blk, 0, stream>>>(x, wk, Kh, nullptr, 0);
    gemm_xwT<<<g, blk, 0, stream>>>(x, wv, Vt, nullptr, 1);
    attn_mfma<<<dim3(512), blk, 0, stream>>>(Qh, Kh, Vt, Yb);
    gemm_xwT<<<g, blk, 0, stream>>>(Yb, wo, out, bo, 2);
}

// Round 3
// 280.599 us; speedup vs baseline: 5.2176x; 2.4736x over previous
//
#include <hip/hip_runtime.h>
#include <math.h>

#define B_DIM 2
#define S_DIM 2048
#define D_DIM 1024
#define H_NUM 16
#define DH    64
#define M_DIM (B_DIM * S_DIM) /* 4096 */

typedef __attribute__((ext_vector_type(8))) short short8;
typedef __attribute__((ext_vector_type(4))) float float4v;
typedef __attribute__((ext_vector_type(4))) unsigned short ushort4v;
typedef unsigned short ushort;

static __device__ __forceinline__ ushort f2bf(float f) {
    unsigned u = __float_as_uint(f);
    u += 0x7fffu + ((u >> 16) & 1u);
    return (ushort)(u >> 16);
}

static __device__ __forceinline__ void gload_lds16(const void* g, void* l) {
    __builtin_amdgcn_global_load_lds(
        (const __attribute__((address_space(1))) void*)g,
        (__attribute__((address_space(3))) void*)l, 16, 0, 0);
}

// ---------------------------------------------------------------------------
// fp32 -> bf16 cast, float4/ushort4 vectorized. n4 = element count / 4.
// ---------------------------------------------------------------------------
__global__ __launch_bounds__(256)
void cast_f32_bf16(const float* __restrict__ s, ushort* __restrict__ d, int n4)
{
    const int i = blockIdx.x * 256 + threadIdx.x;
    if (i < n4) {
        const float4 v = ((const float4*)s)[i];
        ushort4v o;
        o[0] = f2bf(v.x); o[1] = f2bf(v.y); o[2] = f2bf(v.z); o[3] = f2bf(v.w);
        ((ushort4v*)d)[i] = o;
    }
}

// ---------------------------------------------------------------------------
// bf16 MFMA GEMM, m97 structure: 128x128 tile, BK=32, global_load_lds w=16,
// 4 waves in 2x2, each wave 64x64 via 4x4 grid of 16x16x32 MFMAs.
// A:[M=4096, K=1024] bf16 row-major. B:[N, K=1024] bf16 row-major.
// mode 0 (N=3072, fused QKV): n>>10 selects dst: 0->Qh [B,H,S,Dh],
//        1->Kh [B,H,S,Dh], 2->Vt [B,H,Dh,S]; all bf16.
// mode 1 (N=1024, out proj): fp32 out[m*1024+n] = acc + bias[n].
// ---------------------------------------------------------------------------
__global__ __launch_bounds__(256)
void gemm_bf16(const ushort* __restrict__ A, const ushort* __restrict__ B,
               ushort* __restrict__ Qh, ushort* __restrict__ Kh,
               ushort* __restrict__ Vt, float* __restrict__ Of,
               const float* __restrict__ bias, int mode)
{
    __shared__ ushort Asm[128 * 32];   // [row][k], 64B rows, lane-order (no pad!)
    __shared__ ushort Bsm[128 * 32];

    const int K  = 1024;
    const int n0 = blockIdx.x * 128;
    const int m0 = blockIdx.y * 128;
    const int t    = threadIdx.x;
    const int w    = t >> 6;
    const int lane = t & 63;
    const int n    = lane & 15;
    const int quad = lane >> 4;
    const int wm = w >> 1, wn = w & 1;

    // staging addresses: load i covers rows w*32+i*16 + (lane>>2), kchunk lane&3
    const int srow = w * 32 + (lane >> 2);
    const int skel = (lane & 3) * 8;

    float4v acc[4][4];
#pragma unroll
    for (int mt = 0; mt < 4; ++mt)
#pragma unroll
        for (int nt = 0; nt < 4; ++nt) acc[mt][nt] = (float4v){0.f, 0.f, 0.f, 0.f};

    for (int kt = 0; kt < K; kt += 32) {
#pragma unroll
        for (int i = 0; i < 2; ++i) {
            gload_lds16(&A[(size_t)(m0 + srow + i * 16) * K + kt + skel],
                        &Asm[(w * 2 + i) * 512]);
            gload_lds16(&B[(size_t)(n0 + srow + i * 16) * K + kt + skel],
                        &Bsm[(w * 2 + i) * 512]);
        }
        __syncthreads();

        short8 af[4], bfr[4];
#pragma unroll
        for (int mt = 0; mt < 4; ++mt)
            af[mt] = *(const short8*)&Asm[(wm * 64 + mt * 16 + n) * 32 + quad * 8];
#pragma unroll
        for (int nt = 0; nt < 4; ++nt)
            bfr[nt] = *(const short8*)&Bsm[(wn * 64 + nt * 16 + n) * 32 + quad * 8];

#pragma unroll
        for (int mt = 0; mt < 4; ++mt)
#pragma unroll
            for (int nt = 0; nt < 4; ++nt)
                acc[mt][nt] = __builtin_amdgcn_mfma_f32_16x16x32_bf16(
                    af[mt], bfr[nt], acc[mt][nt], 0, 0, 0);
        __syncthreads();
    }

    if (mode == 0) {
        const int wid = n0 >> 10;           // 0=Q 1=K 2=V (constant per block)
        ushort* dstQK = (wid == 0) ? Qh : Kh;
#pragma unroll
        for (int mt = 0; mt < 4; ++mt) {
            const int m = m0 + wm * 64 + mt * 16 + quad * 4;   // +r
            const int b = m >> 11, s = m & (S_DIM - 1);
#pragma unroll
            for (int nt = 0; nt < 4; ++nt) {
                const int ng = (n0 & 1023) + wn * 64 + nt * 16 + n;
                const int h = ng >> 6, d = ng & 63;
                const int bh = b * H_NUM + h;
                if (wid < 2) {
#pragma unroll
                    for (int r = 0; r < 4; ++r)
                        dstQK[(((size_t)bh * S_DIM + s + r) << 6) + d] =
                            f2bf(acc[mt][nt][r]);
                } else {
                    ushort4v p;
#pragma unroll
                    for (int r = 0; r < 4; ++r) p[r] = f2bf(acc[mt][nt][r]);
                    *(ushort4v*)&Vt[(((size_t)bh * DH + d) << 11) + s] = p;
                }
            }
        }
    } else {
#pragma unroll
        for (int mt = 0; mt < 4; ++mt) {
            const int m = m0 + wm * 64 + mt * 16 + quad * 4;
#pragma unroll
            for (int nt = 0; nt < 4; ++nt) {
                const int ng = n0 + wn * 64 + nt * 16 + n;
                const float bv = bias[ng];
#pragma unroll
                for (int r = 0; r < 4; ++r)
                    Of[(size_t)(m + r) * D_DIM + ng] = acc[mt][nt][r] + bv;
            }
        }
    }
}

// ---------------------------------------------------------------------------
// MFMA flash attention (unchanged structure from round 2; now emits bf16 Y).
// ---------------------------------------------------------------------------
#define P_LD 72

__global__ __launch_bounds__(256)
void attn_mfma(const ushort* __restrict__ Qh, const ushort* __restrict__ Kh,
               const ushort* __restrict__ Vt, ushort* __restrict__ Yh)
{
    __shared__ short Pb[4][2][16][P_LD];

    const int w    = threadIdx.x >> 6;
    const int lane = threadIdx.x & 63;
    const int n    = lane & 15;
    const int quad = lane >> 4;

    const int wave_id = blockIdx.x * 4 + w;
    const int bh    = wave_id >> 6;
    const int qbase = (wave_id & 63) * 32;
    const int b     = bh >> 4;
    const int h     = bh & (H_NUM - 1);

    const ushort* Qb = Qh + (((size_t)bh * S_DIM) << 6);
    const ushort* Kb = Kh + (((size_t)bh * S_DIM) << 6);
    const ushort* Vb = Vt + (((size_t)bh * DH) << 11);

    short8 qa[2][2];
#pragma unroll
    for (int mt = 0; mt < 2; ++mt)
#pragma unroll
        for (int kc = 0; kc < 2; ++kc)
            qa[mt][kc] = *(const short8*)&Qb[((size_t)(qbase + mt * 16 + n) << 6) + kc * 32 + quad * 8];

    float4v O[2][4];
    float   mrow[2][4], lrow[2][4];
#pragma unroll
    for (int mt = 0; mt < 2; ++mt) {
#pragma unroll
        for (int nt = 0; nt < 4; ++nt) O[mt][nt] = (float4v){0.f, 0.f, 0.f, 0.f};
#pragma unroll
        for (int r = 0; r < 4; ++r) { mrow[mt][r] = -1e30f; lrow[mt][r] = 0.f; }
    }

    const float SCALE = 0.125f;

    for (int kb = 0; kb < S_DIM / 64; ++kb) {
        const int key0 = kb * 64;
        short8 kf[4][2];
#pragma unroll
        for (int ct = 0; ct < 4; ++ct)
#pragma unroll
            for (int kc = 0; kc < 2; ++kc)
                kf[ct][kc] = *(const short8*)&Kb[((size_t)(key0 + ct * 16 + n) << 6) + kc * 32 + quad * 8];

        float4v s[2][4];
#pragma unroll
        for (int mt = 0; mt < 2; ++mt)
#pragma unroll
            for (int ct = 0; ct < 4; ++ct) {
                float4v a = (float4v){0.f, 0.f, 0.f, 0.f};
                a = __builtin_amdgcn_mfma_f32_16x16x32_bf16(qa[mt][0], kf[ct][0], a, 0, 0, 0);
                a = __builtin_amdgcn_mfma_f32_16x16x32_bf16(qa[mt][1], kf[ct][1], a, 0, 0, 0);
                s[mt][ct] = a;
            }

        short8 vf[4][2];
#pragma unroll
        for (int nt = 0; nt < 4; ++nt)
#pragma unroll
            for (int kc = 0; kc < 2; ++kc)
                vf[nt][kc] = *(const short8*)&Vb[((size_t)(nt * 16 + n) << 11) + key0 + kc * 32 + quad * 8];

#pragma unroll
        for (int mt = 0; mt < 2; ++mt) {
#pragma unroll
            for (int r = 0; r < 4; ++r) {
                const float a0 = s[mt][0][r] * SCALE;
                const float a1 = s[mt][1][r] * SCALE;
                const float a2 = s[mt][2][r] * SCALE;
                const float a3 = s[mt][3][r] * SCALE;
                float cm = fmaxf(fmaxf(a0, a1), fmaxf(a2, a3));
                cm = fmaxf(cm, __shfl_xor(cm, 1, 64));
                cm = fmaxf(cm, __shfl_xor(cm, 2, 64));
                cm = fmaxf(cm, __shfl_xor(cm, 4, 64));
                cm = fmaxf(cm, __shfl_xor(cm, 8, 64));
                const float mnew  = fmaxf(mrow[mt][r], cm);
                const float alpha = __expf(mrow[mt][r] - mnew);
                mrow[mt][r] = mnew;
                const float p0 = __expf(a0 - mnew);
                const float p1 = __expf(a1 - mnew);
                const float p2 = __expf(a2 - mnew);
                const float p3 = __expf(a3 - mnew);
                lrow[mt][r] = lrow[mt][r] * alpha + (p0 + p1 + p2 + p3);
#pragma unroll
                for (int nt = 0; nt < 4; ++nt) O[mt][nt][r] *= alpha;
                const int prow = quad * 4 + r;
                Pb[w][mt][prow][0 * 16 + n] = (short)f2bf(p0);
                Pb[w][mt][prow][1 * 16 + n] = (short)f2bf(p1);
                Pb[w][mt][prow][2 * 16 + n] = (short)f2bf(p2);
                Pb[w][mt][prow][3 * 16 + n] = (short)f2bf(p3);
            }
            const short8 pa0 = *(const short8*)&Pb[w][mt][n][quad * 8];
            const short8 pa1 = *(const short8*)&Pb[w][mt][n][32 + quad * 8];
#pragma unroll
            for (int nt = 0; nt < 4; ++nt) {
                O[mt][nt] = __builtin_amdgcn_mfma_f32_16x16x32_bf16(pa0, vf[nt][0], O[mt][nt], 0, 0, 0);
                O[mt][nt] = __builtin_amdgcn_mfma_f32_16x16x32_bf16(pa1, vf[nt][1], O[mt][nt], 0, 0, 0);
            }
        }
    }

#pragma unroll
    for (int mt = 0; mt < 2; ++mt) {
        float linv[4];
#pragma unroll
        for (int r = 0; r < 4; ++r) {
            float ls = lrow[mt][r];
            ls += __shfl_xor(ls, 1, 64);
            ls += __shfl_xor(ls, 2, 64);
            ls += __shfl_xor(ls, 4, 64);
            ls += __shfl_xor(ls, 8, 64);
            linv[r] = 1.f / ls;
        }
#pragma unroll
        for (int nt = 0; nt < 4; ++nt)
#pragma unroll
            for (int r = 0; r < 4; ++r) {
                const int q = qbase + mt * 16 + quad * 4 + r;
                Yh[((size_t)(b * S_DIM + q) << 10) + h * DH + nt * 16 + n] =
                    f2bf(O[mt][nt][r] * linv[r]);
            }
    }
}

// ---------------------------------------------------------------------------
extern "C" void kernel_launch(void* const* d_in, const int* in_sizes, int n_in,
                              void* d_out, int out_size, void* d_ws, size_t ws_size,
                              hipStream_t stream)
{
    const float* x  = (const float*)d_in[0];
    const float* wq = (const float*)d_in[1];
    const float* wk = (const float*)d_in[2];
    const float* wv = (const float*)d_in[3];
    const float* wo = (const float*)d_in[4];
    const float* bo = (const float*)d_in[5];
    float* out = (float*)d_out;

    const size_t MD = (size_t)M_DIM * D_DIM;      // 4M elements
    const size_t WD = (size_t)D_DIM * D_DIM;      // 1M elements
    ushort* xh  = (ushort*)d_ws;      // 8 MB  [M,K] bf16
    ushort* Wh  = xh + MD;            // 6 MB  [3072,1024] bf16 (wq|wk|wv)
    ushort* Woh = Wh + 3 * WD;        // 2 MB  [1024,1024] bf16
    ushort* Qh  = Woh + WD;           // 8 MB  [B,H,S,Dh] bf16
    ushort* Kh  = Qh + MD;            // 8 MB  [B,H,S,Dh] bf16
    ushort* Vt  = Kh + MD;            // 8 MB  [B,H,Dh,S] bf16
    ushort* Yh  = Vt + MD;            // 8 MB  [M,D] bf16
    if (ws_size < 48u * 1024u * 1024u) return;

    dim3 blk(256);
    cast_f32_bf16<<<dim3((int)(MD / 4 / 256)), blk, 0, stream>>>(x,  xh,           (int)(MD / 4));
    cast_f32_bf16<<<dim3((int)(WD / 4 / 256)), blk, 0, stream>>>(wq, Wh,           (int)(WD / 4));
    cast_f32_bf16<<<dim3((int)(WD / 4 / 256)), blk, 0, stream>>>(wk, Wh + WD,      (int)(WD / 4));
    cast_f32_bf16<<<dim3((int)(WD / 4 / 256)), blk, 0, stream>>>(wv, Wh + 2 * WD,  (int)(WD / 4));
    cast_f32_bf16<<<dim3((int)(WD / 4 / 256)), blk, 0, stream>>>(wo, Woh,          (int)(WD / 4));

    gemm_bf16<<<dim3(24, 32), blk, 0, stream>>>(xh, Wh, Qh, Kh, Vt, nullptr, nullptr, 0);
    attn_mfma<<<dim3(512), blk, 0, stream>>>(Qh, Kh, Vt, Yh);
    gemm_bf16<<<dim3(8, 32), blk, 0, stream>>>(Yh, Woh, nullptr, nullptr, nullptr, out, bo, 1);
}